// Round 2
// baseline (410.512 us; speedup 1.0000x reference)
//
#include <hip/hip_runtime.h>

// ---------------------------------------------------------------------------
// CrossAttention: B=32, C=256, H=W=32 (HW=1024), Cq=128
// out[b,c,i] = sum_j v[b,c,j] * softmax_j(q^T k)[i,j] + x1[b,c,i]
//   q = Wq @ x1 + bq            [b,128,1024]
//   k = Wk[:, :256] @ x2 + kadd (pyramid channels fold into per-region bias)
//   v = Wv @ x2 + bv            [b,256,1024]
// bf16 MFMA (16x16x32), f32 accum; flash attention, barrier-free attn kernel.
// ---------------------------------------------------------------------------

typedef __attribute__((ext_vector_type(8))) short short8;    // 8 bf16 (4 VGPR)
typedef __attribute__((ext_vector_type(4))) float f32x4;     // 4 f32 acc

#define MFMA(a, b, c) __builtin_amdgcn_mfma_f32_16x16x32_bf16((a), (b), (c), 0, 0, 0)

__device__ __forceinline__ unsigned short f2bf(float f) {
    unsigned u = __builtin_bit_cast(unsigned, f);
    u = (u + 0x7FFFu + ((u >> 16) & 1u)) >> 16;   // round-to-nearest-even
    return (unsigned short)u;
}

__device__ __forceinline__ short8 ld8(const unsigned short* p) {
    return *reinterpret_cast<const short8*>(p);
}

// ------------------ f32 -> bf16 convert (all 3 weight mats) ----------------
__global__ __launch_bounds__(256) void wconv_kernel(const float* Wq, const float* Wk,
                                                    const float* Wv,
                                                    unsigned short* wqb, unsigned short* wkb,
                                                    unsigned short* wvb) {
    int i = blockIdx.x * 256 + threadIdx.x;   // 0 .. 229375
    if (i < 32768) { wqb[i] = f2bf(Wq[i]); return; }
    if (i < 163840) { wkb[i - 32768] = f2bf(Wk[i - 32768]); return; }
    wvb[i - 163840] = f2bf(Wv[i - 163840]);
}

// ------------------- transpose [b][c=256][n=1024] f32 -> [b][n][c] bf16 ----
__global__ __launch_bounds__(256) void transpose_kernel(const float* __restrict__ x,
                                                        unsigned short* __restrict__ xt) {
    __shared__ unsigned short tile[64][65];
    int b = blockIdx.z, c0 = blockIdx.y * 64, n0 = blockIdx.x * 64;
    const float* src = x + ((size_t)b * 256 + c0) * 1024 + n0;
    int tid = threadIdx.x;
#pragma unroll
    for (int it = 0; it < 16; ++it) {
        int idx = it * 256 + tid;
        int cl = idx >> 6, nl = idx & 63;
        tile[cl][nl] = f2bf(src[(size_t)cl * 1024 + nl]);
    }
    __syncthreads();
    int nl = tid >> 2, cs = (tid & 3) * 16;
    unsigned short buf[16];
#pragma unroll
    for (int j = 0; j < 16; ++j) buf[j] = tile[cs + j][nl];
    unsigned int w[8];
#pragma unroll
    for (int k = 0; k < 8; ++k) w[k] = (unsigned)buf[2 * k] | ((unsigned)buf[2 * k + 1] << 16);
    unsigned short* dst = xt + ((size_t)b * 1024 + n0 + nl) * 256 + c0 + cs;
    uint4 u0; u0.x = w[0]; u0.y = w[1]; u0.z = w[2]; u0.w = w[3];
    uint4 u1; u1.x = w[4]; u1.y = w[5]; u1.z = w[6]; u1.w = w[7];
    reinterpret_cast<uint4*>(dst)[0] = u0;
    reinterpret_cast<uint4*>(dst)[1] = u1;
}

// ------------------------- pyramid pools of x2 -----------------------------
__global__ __launch_bounds__(64) void pool_kernel(const float* __restrict__ x2,
                                                  float* __restrict__ p1,
                                                  float* __restrict__ p2,
                                                  float* __restrict__ p4) {
    int bc = blockIdx.x;
    int t = threadIdx.x;
    const float* src = x2 + (size_t)bc * 1024;
    int dh = t >> 3, dw = t & 7;
    float s[16];
#pragma unroll
    for (int r = 0; r < 16; ++r)
        s[r] = src[((r >> 2) * 8 + dh) * 32 + (r & 3) * 8 + dw];
#pragma unroll
    for (int r = 0; r < 16; ++r) {
        float v = s[r];
        v += __shfl_xor(v, 1);  v += __shfl_xor(v, 2);  v += __shfl_xor(v, 4);
        v += __shfl_xor(v, 8);  v += __shfl_xor(v, 16); v += __shfl_xor(v, 32);
        s[r] = v;
    }
    if (t == 0) {
        float sq[4];
#pragma unroll
        for (int j = 0; j < 4; ++j) {
            int jh = j >> 1, jw = j & 1;
            sq[j] = s[8 * jh + 2 * jw] + s[8 * jh + 2 * jw + 1] +
                    s[8 * jh + 4 + 2 * jw] + s[8 * jh + 4 + 2 * jw + 1];
            p2[(size_t)bc * 4 + j] = sq[j] * (1.f / 256.f);
        }
#pragma unroll
        for (int r = 0; r < 16; ++r) p4[(size_t)bc * 16 + r] = s[r] * (1.f / 64.f);
        p1[bc] = (sq[0] + sq[1] + sq[2] + sq[3]) * (1.f / 1024.f);
    }
}

// -------- kadd[b][o][r16] = bk[o] + Wk[:,256:]·(pooled channels for r) -----
__global__ __launch_bounds__(256) void kadd_kernel(const float* __restrict__ Wk,
                                                   const float* __restrict__ bk,
                                                   const float* __restrict__ p1,
                                                   const float* __restrict__ p2,
                                                   const float* __restrict__ p4,
                                                   float* __restrict__ kadd) {
    int b = blockIdx.x >> 7, o = blockIdx.x & 127;
    int tid = threadIdx.x;
    const float* wr = Wk + (size_t)o * 1024;
    int c = tid;
    size_t bc = (size_t)b * 256 + c;
    float vals[21];
    vals[0] = wr[256 + c] * p1[bc];
    float w2 = wr[512 + c], w4 = wr[768 + c];
#pragma unroll
    for (int j = 0; j < 4; ++j) vals[1 + j] = w2 * p2[bc * 4 + j];
#pragma unroll
    for (int r = 0; r < 16; ++r) vals[5 + r] = w4 * p4[bc * 16 + r];

    int lane = tid & 63, wid = tid >> 6;
    __shared__ float red[21][4];
    __shared__ float tot[21];
#pragma unroll
    for (int k = 0; k < 21; ++k) {
        float v = vals[k];
        v += __shfl_xor(v, 1);  v += __shfl_xor(v, 2);  v += __shfl_xor(v, 4);
        v += __shfl_xor(v, 8);  v += __shfl_xor(v, 16); v += __shfl_xor(v, 32);
        if (lane == 0) red[k][wid] = v;
    }
    __syncthreads();
    if (tid < 21) tot[tid] = red[tid][0] + red[tid][1] + red[tid][2] + red[tid][3];
    __syncthreads();
    if (tid < 16) {
        int r = tid;
        int rr = ((r >> 2) >> 1) * 2 + ((r & 3) >> 1);
        kadd[((size_t)(b * 128 + o)) * 16 + r] = bk[o] + tot[0] + tot[1 + rr] + tot[5 + r];
    }
}

// --------------------------- projection GEMMs ------------------------------
template <int MODE>
__global__ __launch_bounds__(256) void gemm_kernel(const unsigned short* __restrict__ A0,
                                                   const unsigned short* __restrict__ B0,
                                                   unsigned short* __restrict__ out0,
                                                   const float* __restrict__ bias,
                                                   const float* __restrict__ kadd) {
    int b = blockIdx.z;
    const unsigned short* A;
    const unsigned short* Bp;
    unsigned short* out;
    int lda, ldb, ldo;
    if (MODE == 0) { A = A0 + (size_t)b * 262144; lda = 256; Bp = B0; ldb = 256;  out = out0 + (size_t)b * 131072; ldo = 128; }
    if (MODE == 1) { A = A0 + (size_t)b * 262144; lda = 256; Bp = B0; ldb = 1024; out = out0 + (size_t)b * 131072; ldo = 128; }
    if (MODE == 2) { A = A0;                      lda = 256; Bp = B0 + (size_t)b * 262144; ldb = 256; out = out0 + (size_t)b * 262144; ldo = 1024; }

    int tid = threadIdx.x;
    int w = tid >> 6, lane = tid & 63;
    int lrow = lane & 15, lk8 = (lane >> 4) * 8;
    int row0 = blockIdx.x * 128 + (w >> 1) * 64;
    int col0 = blockIdx.y * 128 + (w & 1) * 64;

    f32x4 z = {0.f, 0.f, 0.f, 0.f};
    f32x4 acc[4][4];
#pragma unroll
    for (int i = 0; i < 4; ++i)
#pragma unroll
        for (int j = 0; j < 4; ++j) acc[i][j] = z;

    for (int kc = 0; kc < 256; kc += 32) {
        short8 af[4], bfr[4];
#pragma unroll
        for (int i = 0; i < 4; ++i)
            af[i] = ld8(A + (size_t)(row0 + i * 16 + lrow) * lda + kc + lk8);
#pragma unroll
        for (int j = 0; j < 4; ++j)
            bfr[j] = ld8(Bp + (size_t)(col0 + j * 16 + lrow) * ldb + kc + lk8);
#pragma unroll
        for (int i = 0; i < 4; ++i)
#pragma unroll
            for (int j = 0; j < 4; ++j) acc[i][j] = MFMA(af[i], bfr[j], acc[i][j]);
    }

#pragma unroll
    for (int i = 0; i < 4; ++i) {
#pragma unroll
        for (int j = 0; j < 4; ++j) {
            int col = col0 + j * 16 + lrow;
#pragma unroll
            for (int r = 0; r < 4; ++r) {
                int row = row0 + i * 16 + (lane >> 4) * 4 + r;
                float val = acc[i][j][r];
                if (MODE == 0) val += bias[col];
                if (MODE == 1) {
                    int h = row >> 5, ww = row & 31;
                    val += kadd[((size_t)(b * 128 + col)) * 16 + ((h >> 3) * 4 + (ww >> 3))];
                }
                if (MODE == 2) val += bias[row];
                out[(size_t)row * ldo + col] = f2bf(val);
            }
        }
    }
}

// --------------------------- flash attention -------------------------------
// block: (b, i-tile of 64); 4 waves x 16 query rows, fully independent
// (plds is per-wave: NO barriers anywhere). j-tile = 64.
// Epilogue: PV acc layout gives 4 consecutive i per lane -> direct float4
// stores fused with residual (no O transpose buffer).
__global__ __launch_bounds__(256) void attn_kernel(const unsigned short* __restrict__ qt,
                                                   const unsigned short* __restrict__ kt,
                                                   const unsigned short* __restrict__ vv,
                                                   const float* __restrict__ x1,
                                                   float* __restrict__ out) {
    int b = blockIdx.x >> 4;
    int i0 = (blockIdx.x & 15) * 64;
    int tid = threadIdx.x;
    int w = tid >> 6, lane = tid & 63;
    int lrow = lane & 15, lk8 = (lane >> 4) * 8;
    int iw = i0 + w * 16;

    __shared__ unsigned short plds[4][16][72];   // per-wave P strip (9.2 KB total)

    const unsigned short* qb = qt + ((size_t)b * 1024 + iw) * 128;
    const unsigned short* kb = kt + (size_t)b * 131072;
    const unsigned short* vb = vv + (size_t)b * 262144;

    short8 qf[4];
#pragma unroll
    for (int cc = 0; cc < 4; ++cc) qf[cc] = ld8(qb + (size_t)lrow * 128 + cc * 32 + lk8);

    f32x4 z = {0.f, 0.f, 0.f, 0.f};
    f32x4 oacc[16];
#pragma unroll
    for (int cb = 0; cb < 16; ++cb) oacc[cb] = z;
    float m_[4] = {-1e30f, -1e30f, -1e30f, -1e30f};
    float l_[4] = {0.f, 0.f, 0.f, 0.f};

    for (int j0 = 0; j0 < 1024; j0 += 64) {
        // ---- S strip: 16 rows x 64 cols ----
        f32x4 s[4];
#pragma unroll
        for (int jb = 0; jb < 4; ++jb) s[jb] = z;
#pragma unroll
        for (int jb = 0; jb < 4; ++jb)
#pragma unroll
            for (int cc = 0; cc < 4; ++cc) {
                short8 kf = ld8(kb + (size_t)(j0 + jb * 16 + lrow) * 128 + cc * 32 + lk8);
                s[jb] = MFMA(qf[cc], kf, s[jb]);
            }

        // ---- online softmax (rows live in 16-lane groups) ----
        float sc[4], rs[4];
#pragma unroll
        for (int r = 0; r < 4; ++r) {
            float t = fmaxf(fmaxf(s[0][r], s[1][r]), fmaxf(s[2][r], s[3][r]));
            t = fmaxf(t, __shfl_xor(t, 1));
            t = fmaxf(t, __shfl_xor(t, 2));
            t = fmaxf(t, __shfl_xor(t, 4));
            t = fmaxf(t, __shfl_xor(t, 8));
            float nm = fmaxf(m_[r], t);
            sc[r] = __expf(m_[r] - nm);
            m_[r] = nm;
            rs[r] = 0.f;
        }
#pragma unroll
        for (int jb = 0; jb < 4; ++jb)
#pragma unroll
            for (int r = 0; r < 4; ++r) {
                float p = __expf(s[jb][r] - m_[r]);
                rs[r] += p;
                plds[w][(lane >> 4) * 4 + r][jb * 16 + lrow] = f2bf(p);
            }
#pragma unroll
        for (int r = 0; r < 4; ++r) {
            float t = rs[r];
            t += __shfl_xor(t, 1);
            t += __shfl_xor(t, 2);
            t += __shfl_xor(t, 4);
            t += __shfl_xor(t, 8);
            l_[r] = l_[r] * sc[r] + t;
        }
#pragma unroll
        for (int cb = 0; cb < 16; ++cb)
#pragma unroll
            for (int r = 0; r < 4; ++r) oacc[cb][r] *= sc[r];

        // same-wave LDS round-trip; compiler inserts lgkmcnt waits, no barrier
        short8 pa0 = ld8(&plds[w][lrow][lk8]);
        short8 pa1 = ld8(&plds[w][lrow][32 + lk8]);

        // ---- PV: O[i,c] += P[i,j] * V[c,j] ----
#pragma unroll
        for (int cb = 0; cb < 16; ++cb) {
            short8 vf0 = ld8(vb + (size_t)(cb * 16 + lrow) * 1024 + j0 + lk8);
            oacc[cb] = MFMA(pa0, vf0, oacc[cb]);
            short8 vf1 = ld8(vb + (size_t)(cb * 16 + lrow) * 1024 + j0 + 32 + lk8);
            oacc[cb] = MFMA(pa1, vf1, oacc[cb]);
        }
    }

    // ---- epilogue: direct float4 stores (4 consecutive i per lane) + x1 ----
    float inv[4];
#pragma unroll
    for (int r = 0; r < 4; ++r) inv[r] = 1.f / l_[r];
    int ib = iw + (lane >> 4) * 4;
#pragma unroll
    for (int cb = 0; cb < 16; ++cb) {
        int c = cb * 16 + lrow;
        size_t g = ((size_t)b * 256 + c) * 1024 + ib;
        f32x4 xv = *reinterpret_cast<const f32x4*>(x1 + g);
        f32x4 res;
#pragma unroll
        for (int r = 0; r < 4; ++r) res[r] = oacc[cb][r] * inv[r] + xv[r];
        *reinterpret_cast<f32x4*>(out + g) = res;
    }
}

// ---------------------------------------------------------------------------
extern "C" void kernel_launch(void* const* d_in, const int* in_sizes, int n_in,
                              void* d_out, int out_size, void* d_ws, size_t ws_size,
                              hipStream_t stream) {
    const float* x1 = (const float*)d_in[0];
    const float* x2 = (const float*)d_in[1];
    const float* Wq = (const float*)d_in[2];
    const float* bq = (const float*)d_in[3];
    const float* Wk = (const float*)d_in[4];
    const float* bk = (const float*)d_in[5];
    const float* Wv = (const float*)d_in[6];
    const float* bv = (const float*)d_in[7];
    float* out = (float*)d_out;

    char* ws = (char*)d_ws;
    unsigned short* x1t = (unsigned short*)(ws + 0);            // 16 MiB
    unsigned short* x2t = (unsigned short*)(ws + 16777216);     // 16 MiB
    unsigned short* qt  = (unsigned short*)(ws + 33554432);     // 8 MiB
    unsigned short* kt  = (unsigned short*)(ws + 41943040);     // 8 MiB
    unsigned short* v   = (unsigned short*)(ws + 50331648);     // 16 MiB
    float* p1   = (float*)(ws + 67108864);                      // 32 KiB
    float* p2   = (float*)(ws + 67141632);                      // 128 KiB
    float* p4   = (float*)(ws + 67272704);                      // 512 KiB
    float* kadd = (float*)(ws + 67796992);                      // 256 KiB
    unsigned short* wqb = (unsigned short*)(ws + 68059136);     // 64 KiB
    unsigned short* wkb = (unsigned short*)(ws + 68124672);     // 256 KiB
    unsigned short* wvb = (unsigned short*)(ws + 68386816);     // 128 KiB

    // weights -> bf16 (single kernel)
    wconv_kernel<<<896, 256, 0, stream>>>(Wq, Wk, Wv, wqb, wkb, wvb);

    // x1,x2 -> transposed bf16 [b][n][c]
    transpose_kernel<<<dim3(16, 4, 32), 256, 0, stream>>>(x1, x1t);
    transpose_kernel<<<dim3(16, 4, 32), 256, 0, stream>>>(x2, x2t);

    // pyramid pools + k-bias fold
    pool_kernel<<<8192, 64, 0, stream>>>(x2, p1, p2, p4);
    kadd_kernel<<<4096, 256, 0, stream>>>(Wk, bk, p1, p2, p4, kadd);

    // projections
    gemm_kernel<0><<<dim3(8, 1, 32), 256, 0, stream>>>(x1t, wqb, qt, bq, nullptr);
    gemm_kernel<1><<<dim3(8, 1, 32), 256, 0, stream>>>(x2t, wkb, kt, nullptr, kadd);
    gemm_kernel<2><<<dim3(2, 8, 32), 256, 0, stream>>>(wvb, x2t, v, bv, nullptr);

    // flash attention + residual
    attn_kernel<<<512, 256, 0, stream>>>(qt, kt, v, x1, out);
}

// Round 3
// 262.832 us; speedup vs baseline: 1.5619x; 1.5619x over previous
//
#include <hip/hip_runtime.h>

// ---------------------------------------------------------------------------
// CrossAttention: B=32, C=256, H=W=32 (HW=1024), Cq=128
// out[b,c,i] = sum_j v[b,c,j] * softmax_j(q^T k)[i,j] + x1[b,c,i]
// bf16 MFMA (16x16x32), f32 accum; flash attention.
// R3: LDS staging via global_load_lds(16B) + XOR swizzle for attn K/V tiles
//     and for projection-GEMM A/B tiles (kills per-MFMA global-load latency).
// ---------------------------------------------------------------------------

typedef __attribute__((ext_vector_type(8))) short short8;    // 8 bf16 (4 VGPR)
typedef __attribute__((ext_vector_type(4))) float f32x4;     // 4 f32 acc

#define MFMA(a, b, c) __builtin_amdgcn_mfma_f32_16x16x32_bf16((a), (b), (c), 0, 0, 0)

// direct-to-LDS 16B load: linear LDS dest (wave-uniform base + lane*16),
// per-lane global source (pre-swizzled)  [guide §5, m97/m104/m173]
#define GLOAD16(gp, lp)                                                        \
    __builtin_amdgcn_global_load_lds(                                          \
        (const __attribute__((address_space(1))) unsigned int*)(gp),           \
        (__attribute__((address_space(3))) unsigned int*)(lp), 16, 0, 0)

__device__ __forceinline__ unsigned short f2bf(float f) {
    unsigned u = __builtin_bit_cast(unsigned, f);
    u = (u + 0x7FFFu + ((u >> 16) & 1u)) >> 16;   // round-to-nearest-even
    return (unsigned short)u;
}

__device__ __forceinline__ short8 ld8(const unsigned short* p) {
    return *reinterpret_cast<const short8*>(p);
}
__device__ __forceinline__ short8 ld8b(const void* base, int byte_off) {
    return *reinterpret_cast<const short8*>((const char*)base + byte_off);
}

// ------------------ f32 -> bf16 convert (all 3 weight mats) ----------------
__global__ __launch_bounds__(256) void wconv_kernel(const float* Wq, const float* Wk,
                                                    const float* Wv,
                                                    unsigned short* wqb, unsigned short* wkb,
                                                    unsigned short* wvb) {
    int i = blockIdx.x * 256 + threadIdx.x;   // 0 .. 229375
    if (i < 32768) { wqb[i] = f2bf(Wq[i]); return; }
    if (i < 163840) { wkb[i - 32768] = f2bf(Wk[i - 32768]); return; }
    wvb[i - 163840] = f2bf(Wv[i - 163840]);
}

// ------------------- transpose [b][c=256][n=1024] f32 -> [b][n][c] bf16 ----
__global__ __launch_bounds__(256) void transpose_kernel(const float* __restrict__ x,
                                                        unsigned short* __restrict__ xt) {
    __shared__ unsigned short tile[64][65];
    int b = blockIdx.z, c0 = blockIdx.y * 64, n0 = blockIdx.x * 64;
    const float* src = x + ((size_t)b * 256 + c0) * 1024 + n0;
    int tid = threadIdx.x;
#pragma unroll
    for (int it = 0; it < 16; ++it) {
        int idx = it * 256 + tid;
        int cl = idx >> 6, nl = idx & 63;
        tile[cl][nl] = f2bf(src[(size_t)cl * 1024 + nl]);
    }
    __syncthreads();
    int nl = tid >> 2, cs = (tid & 3) * 16;
    unsigned short buf[16];
#pragma unroll
    for (int j = 0; j < 16; ++j) buf[j] = tile[cs + j][nl];
    unsigned int w[8];
#pragma unroll
    for (int k = 0; k < 8; ++k) w[k] = (unsigned)buf[2 * k] | ((unsigned)buf[2 * k + 1] << 16);
    unsigned short* dst = xt + ((size_t)b * 1024 + n0 + nl) * 256 + c0 + cs;
    uint4 u0; u0.x = w[0]; u0.y = w[1]; u0.z = w[2]; u0.w = w[3];
    uint4 u1; u1.x = w[4]; u1.y = w[5]; u1.z = w[6]; u1.w = w[7];
    reinterpret_cast<uint4*>(dst)[0] = u0;
    reinterpret_cast<uint4*>(dst)[1] = u1;
}

// ------------------------- pyramid pools of x2 -----------------------------
__global__ __launch_bounds__(64) void pool_kernel(const float* __restrict__ x2,
                                                  float* __restrict__ p1,
                                                  float* __restrict__ p2,
                                                  float* __restrict__ p4) {
    int bc = blockIdx.x;
    int t = threadIdx.x;
    const float* src = x2 + (size_t)bc * 1024;
    int dh = t >> 3, dw = t & 7;
    float s[16];
#pragma unroll
    for (int r = 0; r < 16; ++r)
        s[r] = src[((r >> 2) * 8 + dh) * 32 + (r & 3) * 8 + dw];
#pragma unroll
    for (int r = 0; r < 16; ++r) {
        float v = s[r];
        v += __shfl_xor(v, 1);  v += __shfl_xor(v, 2);  v += __shfl_xor(v, 4);
        v += __shfl_xor(v, 8);  v += __shfl_xor(v, 16); v += __shfl_xor(v, 32);
        s[r] = v;
    }
    if (t == 0) {
        float sq[4];
#pragma unroll
        for (int j = 0; j < 4; ++j) {
            int jh = j >> 1, jw = j & 1;
            sq[j] = s[8 * jh + 2 * jw] + s[8 * jh + 2 * jw + 1] +
                    s[8 * jh + 4 + 2 * jw] + s[8 * jh + 4 + 2 * jw + 1];
            p2[(size_t)bc * 4 + j] = sq[j] * (1.f / 256.f);
        }
#pragma unroll
        for (int r = 0; r < 16; ++r) p4[(size_t)bc * 16 + r] = s[r] * (1.f / 64.f);
        p1[bc] = (sq[0] + sq[1] + sq[2] + sq[3]) * (1.f / 1024.f);
    }
}

// -------- kadd[b][o][r16] = bk[o] + Wk[:,256:]·(pooled channels for r) -----
__global__ __launch_bounds__(256) void kadd_kernel(const float* __restrict__ Wk,
                                                   const float* __restrict__ bk,
                                                   const float* __restrict__ p1,
                                                   const float* __restrict__ p2,
                                                   const float* __restrict__ p4,
                                                   float* __restrict__ kadd) {
    int b = blockIdx.x >> 7, o = blockIdx.x & 127;
    int tid = threadIdx.x;
    const float* wr = Wk + (size_t)o * 1024;
    int c = tid;
    size_t bc = (size_t)b * 256 + c;
    float vals[21];
    vals[0] = wr[256 + c] * p1[bc];
    float w2 = wr[512 + c], w4 = wr[768 + c];
#pragma unroll
    for (int j = 0; j < 4; ++j) vals[1 + j] = w2 * p2[bc * 4 + j];
#pragma unroll
    for (int r = 0; r < 16; ++r) vals[5 + r] = w4 * p4[bc * 16 + r];

    int lane = tid & 63, wid = tid >> 6;
    __shared__ float red[21][4];
    __shared__ float tot[21];
#pragma unroll
    for (int k = 0; k < 21; ++k) {
        float v = vals[k];
        v += __shfl_xor(v, 1);  v += __shfl_xor(v, 2);  v += __shfl_xor(v, 4);
        v += __shfl_xor(v, 8);  v += __shfl_xor(v, 16); v += __shfl_xor(v, 32);
        if (lane == 0) red[k][wid] = v;
    }
    __syncthreads();
    if (tid < 21) tot[tid] = red[tid][0] + red[tid][1] + red[tid][2] + red[tid][3];
    __syncthreads();
    if (tid < 16) {
        int r = tid;
        int rr = ((r >> 2) >> 1) * 2 + ((r & 3) >> 1);
        kadd[((size_t)(b * 128 + o)) * 16 + r] = bk[o] + tot[0] + tot[1 + rr] + tot[5 + r];
    }
}

// --------------------------- projection GEMMs ------------------------------
// 128x128 tile, K=256 in 4 steps of BK=64; A/B tiles staged in LDS via
// global_load_lds with XOR swizzle (byte ^= (row&7)<<4 within 128B rows).
template <int MODE>
__global__ __launch_bounds__(256) void gemm_kernel(const unsigned short* __restrict__ A0,
                                                   const unsigned short* __restrict__ B0,
                                                   unsigned short* __restrict__ out0,
                                                   const float* __restrict__ bias,
                                                   const float* __restrict__ kadd) {
    int b = blockIdx.z;
    const unsigned short* A;
    const unsigned short* Bp;
    unsigned short* out;
    int lda, ldb, ldo;
    if (MODE == 0) { A = A0 + (size_t)b * 262144; lda = 256; Bp = B0; ldb = 256;  out = out0 + (size_t)b * 131072; ldo = 128; }
    if (MODE == 1) { A = A0 + (size_t)b * 262144; lda = 256; Bp = B0; ldb = 1024; out = out0 + (size_t)b * 131072; ldo = 128; }
    if (MODE == 2) { A = A0;                      lda = 256; Bp = B0 + (size_t)b * 262144; ldb = 256; out = out0 + (size_t)b * 262144; ldo = 1024; }

    __shared__ unsigned short alds[128 * 64];   // 16 KB, 128B rows, swizzled
    __shared__ unsigned short blds[128 * 64];   // 16 KB

    int tid = threadIdx.x;
    int w = tid >> 6, lane = tid & 63;
    int lrow = lane & 15, lk8 = (lane >> 4) * 8;
    int lk16b = lk8 * 2;
    int swl = (lrow & 7) << 4;
    int row0 = blockIdx.x * 128;
    int col0 = blockIdx.y * 128;
    int wr = (w >> 1) * 64, wc = (w & 1) * 64;

    // per-thread staging geometry (constant across k-steps)
    int soff = w * 1024 + (lane << 4);          // byte offset within a 4KB chunk
    int srow = soff >> 7;                       // row contribution (per it: +32 rows)
    int scol = ((soff & 127) ^ ((srow & 7) << 4)) >> 1;   // swizzled element col

    f32x4 z = {0.f, 0.f, 0.f, 0.f};
    f32x4 acc[4][4];
#pragma unroll
    for (int i = 0; i < 4; ++i)
#pragma unroll
        for (int j = 0; j < 4; ++j) acc[i][j] = z;

    for (int kc = 0; kc < 256; kc += 64) {
#pragma unroll
        for (int it = 0; it < 4; ++it) {
            int row = it * 32 + srow;
            GLOAD16(A + (size_t)(row0 + row) * lda + kc + scol,
                    (char*)alds + it * 4096 + w * 1024);
            GLOAD16(Bp + (size_t)(col0 + row) * ldb + kc + scol,
                    (char*)blds + it * 4096 + w * 1024);
        }
        asm volatile("s_waitcnt vmcnt(0)" ::: "memory");
        __syncthreads();

#pragma unroll
        for (int kh = 0; kh < 2; ++kh) {
            short8 af[4], bfr[4];
#pragma unroll
            for (int i = 0; i < 4; ++i)
                af[i] = ld8b(alds, ((wr + i * 16 + lrow) << 7) + (((kh << 6) + lk16b) ^ swl));
#pragma unroll
            for (int j = 0; j < 4; ++j)
                bfr[j] = ld8b(blds, ((wc + j * 16 + lrow) << 7) + (((kh << 6) + lk16b) ^ swl));
#pragma unroll
            for (int i = 0; i < 4; ++i)
#pragma unroll
                for (int j = 0; j < 4; ++j) acc[i][j] = MFMA(af[i], bfr[j], acc[i][j]);
        }
        __syncthreads();
    }

#pragma unroll
    for (int i = 0; i < 4; ++i) {
#pragma unroll
        for (int j = 0; j < 4; ++j) {
            int col = col0 + wc + j * 16 + lrow;
#pragma unroll
            for (int r = 0; r < 4; ++r) {
                int row = row0 + wr + i * 16 + (lane >> 4) * 4 + r;
                float val = acc[i][j][r];
                if (MODE == 0) val += bias[col];
                if (MODE == 1) {
                    int h = row >> 5, ww = row & 31;
                    val += kadd[((size_t)(b * 128 + col)) * 16 + ((h >> 3) * 4 + (ww >> 3))];
                }
                if (MODE == 2) val += bias[row];
                out[(size_t)row * ldo + col] = f2bf(val);
            }
        }
    }
}

// --------------------------- flash attention -------------------------------
// block: (b, i-tile of 64); 4 waves x 16 query rows. j-tile = 64.
// K tile (64x128, 16KB) and V tile (256x64, 32KB) staged once per block per
// j-step via global_load_lds + XOR swizzle; 2 barriers per j-step.
__global__ __launch_bounds__(256) void attn_kernel(const unsigned short* __restrict__ qt,
                                                   const unsigned short* __restrict__ kt,
                                                   const unsigned short* __restrict__ vv,
                                                   const float* __restrict__ x1,
                                                   float* __restrict__ out) {
    int b = blockIdx.x >> 4;
    int i0 = (blockIdx.x & 15) * 64;
    int tid = threadIdx.x;
    int w = tid >> 6, lane = tid & 63;
    int lrow = lane & 15, lk8 = (lane >> 4) * 8;
    int lk16b = lk8 * 2;
    int swl = (lrow & 7) << 4;
    int iw = i0 + w * 16;

    __shared__ unsigned short klds[64 * 128];    // 16 KB, 256B rows, swizzled
    __shared__ unsigned short vlds[256 * 64];    // 32 KB, 128B rows, swizzled
    __shared__ unsigned short plds[4][16][72];   // per-wave P strip (9.2 KB)

    const unsigned short* qb = qt + ((size_t)b * 1024 + iw) * 128;
    const unsigned short* kb = kt + (size_t)b * 131072;
    const unsigned short* vb = vv + (size_t)b * 262144;

    short8 qf[4];
#pragma unroll
    for (int cc = 0; cc < 4; ++cc) qf[cc] = ld8(qb + (size_t)lrow * 128 + cc * 32 + lk8);

    // staging geometry (per-thread constants)
    int soff = w * 1024 + (lane << 4);
    int krow0 = soff >> 8;                 // K: 256B rows; per it: +16 rows
    int kcb = soff & 255;
    int kcol = (kcb ^ ((krow0 & 7) << 4)) >> 1;   // krow&7 == krow0&7 (it adds 16)
    int vrow0 = soff >> 7;                 // V: 128B rows; per it: +32 rows
    int vcb = soff & 127;
    int vcol = (vcb ^ ((vrow0 & 7) << 4)) >> 1;   // vrow&7 == vrow0&7 (it adds 32)

    f32x4 z = {0.f, 0.f, 0.f, 0.f};
    f32x4 oacc[16];
#pragma unroll
    for (int cb = 0; cb < 16; ++cb) oacc[cb] = z;
    float m_[4] = {-1e30f, -1e30f, -1e30f, -1e30f};
    float l_[4] = {0.f, 0.f, 0.f, 0.f};

    for (int j0 = 0; j0 < 1024; j0 += 64) {
        // ---- stage K (4x) + V (8x) ----
#pragma unroll
        for (int it = 0; it < 4; ++it) {
            int row = it * 16 + krow0;
            GLOAD16(kb + (size_t)(j0 + row) * 128 + kcol,
                    (char*)klds + it * 4096 + w * 1024);
        }
#pragma unroll
        for (int it = 0; it < 8; ++it) {
            int row = it * 32 + vrow0;
            GLOAD16(vb + (size_t)row * 1024 + j0 + vcol,
                    (char*)vlds + it * 4096 + w * 1024);
        }
        asm volatile("s_waitcnt vmcnt(0)" ::: "memory");
        __syncthreads();

        // ---- S strip: 16 rows x 64 cols (K from LDS) ----
        f32x4 s[4];
#pragma unroll
        for (int jb = 0; jb < 4; ++jb) s[jb] = z;
#pragma unroll
        for (int jb = 0; jb < 4; ++jb) {
            int jrow = jb * 16 + lrow;
#pragma unroll
            for (int cc = 0; cc < 4; ++cc) {
                short8 kf = ld8b(klds, (jrow << 8) + (((cc << 6) + lk16b) ^ swl));
                s[jb] = MFMA(qf[cc], kf, s[jb]);
            }
        }

        // ---- online softmax (rows live in 16-lane groups) ----
        float sc[4], rs[4];
#pragma unroll
        for (int r = 0; r < 4; ++r) {
            float t = fmaxf(fmaxf(s[0][r], s[1][r]), fmaxf(s[2][r], s[3][r]));
            t = fmaxf(t, __shfl_xor(t, 1));
            t = fmaxf(t, __shfl_xor(t, 2));
            t = fmaxf(t, __shfl_xor(t, 4));
            t = fmaxf(t, __shfl_xor(t, 8));
            float nm = fmaxf(m_[r], t);
            sc[r] = __expf(m_[r] - nm);
            m_[r] = nm;
            rs[r] = 0.f;
        }
#pragma unroll
        for (int jb = 0; jb < 4; ++jb)
#pragma unroll
            for (int r = 0; r < 4; ++r) {
                float p = __expf(s[jb][r] - m_[r]);
                rs[r] += p;
                plds[w][(lane >> 4) * 4 + r][jb * 16 + lrow] = f2bf(p);
            }
#pragma unroll
        for (int r = 0; r < 4; ++r) {
            float t = rs[r];
            t += __shfl_xor(t, 1);
            t += __shfl_xor(t, 2);
            t += __shfl_xor(t, 4);
            t += __shfl_xor(t, 8);
            l_[r] = l_[r] * sc[r] + t;
        }
#pragma unroll
        for (int cb = 0; cb < 16; ++cb)
#pragma unroll
            for (int r = 0; r < 4; ++r) oacc[cb][r] *= sc[r];

        // same-wave LDS round-trip (lgkmcnt-ordered, no barrier needed)
        short8 pa0 = ld8(&plds[w][lrow][lk8]);
        short8 pa1 = ld8(&plds[w][lrow][32 + lk8]);

        // ---- PV: O[i,c] += P[i,j] * V[c,j] (V from LDS) ----
#pragma unroll
        for (int cb = 0; cb < 16; ++cb) {
            int c = cb * 16 + lrow;
            short8 vf0 = ld8b(vlds, (c << 7) + (lk16b ^ swl));
            oacc[cb] = MFMA(pa0, vf0, oacc[cb]);
            short8 vf1 = ld8b(vlds, (c << 7) + ((64 + lk16b) ^ swl));
            oacc[cb] = MFMA(pa1, vf1, oacc[cb]);
        }
        __syncthreads();   // all reads done before next j-step overwrites LDS
    }

    // ---- epilogue: direct float4 stores (4 consecutive i per lane) + x1 ----
    float inv[4];
#pragma unroll
    for (int r = 0; r < 4; ++r) inv[r] = 1.f / l_[r];
    int ib = iw + (lane >> 4) * 4;
#pragma unroll
    for (int cb = 0; cb < 16; ++cb) {
        int c = cb * 16 + lrow;
        size_t g = ((size_t)b * 256 + c) * 1024 + ib;
        f32x4 xv = *reinterpret_cast<const f32x4*>(x1 + g);
        f32x4 res;
#pragma unroll
        for (int r = 0; r < 4; ++r) res[r] = oacc[cb][r] * inv[r] + xv[r];
        *reinterpret_cast<f32x4*>(out + g) = res;
    }
}

// ---------------------------------------------------------------------------
extern "C" void kernel_launch(void* const* d_in, const int* in_sizes, int n_in,
                              void* d_out, int out_size, void* d_ws, size_t ws_size,
                              hipStream_t stream) {
    const float* x1 = (const float*)d_in[0];
    const float* x2 = (const float*)d_in[1];
    const float* Wq = (const float*)d_in[2];
    const float* bq = (const float*)d_in[3];
    const float* Wk = (const float*)d_in[4];
    const float* bk = (const float*)d_in[5];
    const float* Wv = (const float*)d_in[6];
    const float* bv = (const float*)d_in[7];
    float* out = (float*)d_out;

    char* ws = (char*)d_ws;
    unsigned short* x1t = (unsigned short*)(ws + 0);            // 16 MiB
    unsigned short* x2t = (unsigned short*)(ws + 16777216);     // 16 MiB
    unsigned short* qt  = (unsigned short*)(ws + 33554432);     // 8 MiB
    unsigned short* kt  = (unsigned short*)(ws + 41943040);     // 8 MiB
    unsigned short* v   = (unsigned short*)(ws + 50331648);     // 16 MiB
    float* p1   = (float*)(ws + 67108864);                      // 32 KiB
    float* p2   = (float*)(ws + 67141632);                      // 128 KiB
    float* p4   = (float*)(ws + 67272704);                      // 512 KiB
    float* kadd = (float*)(ws + 67796992);                      // 256 KiB
    unsigned short* wqb = (unsigned short*)(ws + 68059136);     // 64 KiB
    unsigned short* wkb = (unsigned short*)(ws + 68124672);     // 256 KiB
    unsigned short* wvb = (unsigned short*)(ws + 68386816);     // 128 KiB

    // weights -> bf16 (single kernel)
    wconv_kernel<<<896, 256, 0, stream>>>(Wq, Wk, Wv, wqb, wkb, wvb);

    // x1,x2 -> transposed bf16 [b][n][c]
    transpose_kernel<<<dim3(16, 4, 32), 256, 0, stream>>>(x1, x1t);
    transpose_kernel<<<dim3(16, 4, 32), 256, 0, stream>>>(x2, x2t);

    // pyramid pools + k-bias fold
    pool_kernel<<<8192, 64, 0, stream>>>(x2, p1, p2, p4);
    kadd_kernel<<<4096, 256, 0, stream>>>(Wk, bk, p1, p2, p4, kadd);

    // projections
    gemm_kernel<0><<<dim3(8, 1, 32), 256, 0, stream>>>(x1t, wqb, qt, bq, nullptr);
    gemm_kernel<1><<<dim3(8, 1, 32), 256, 0, stream>>>(x2t, wkb, kt, nullptr, kadd);
    gemm_kernel<2><<<dim3(2, 8, 32), 256, 0, stream>>>(wvb, x2t, v, bv, nullptr);

    // flash attention + residual
    attn_kernel<<<512, 256, 0, stream>>>(qt, kt, v, x1, out);
}

// Round 4
// 261.325 us; speedup vs baseline: 1.5709x; 1.0058x over previous
//
#include <hip/hip_runtime.h>

// ---------------------------------------------------------------------------
// CrossAttention: B=32, C=256, H=W=32 (HW=1024), Cq=128
// out[b,c,i] = sum_j v[b,c,j] * softmax_j(q^T k)[i,j] + x1[b,c,i]
// R4: 4 kernels total. Fused transpose+convert into GEMM staging (1 launch
//     for q/k/v). Attn: XCD-affinity b-mapping, K double-buffer + counted
//     vmcnt pipeline (V fetch overlaps QK/softmax), defer-max softmax.
// ---------------------------------------------------------------------------

typedef __attribute__((ext_vector_type(8))) short short8;    // 8 bf16
typedef __attribute__((ext_vector_type(4))) float f32x4;

#define MFMA(a, b, c) __builtin_amdgcn_mfma_f32_16x16x32_bf16((a), (b), (c), 0, 0, 0)

#define GLOAD16(gp, lp)                                                        \
    __builtin_amdgcn_global_load_lds(                                          \
        (const __attribute__((address_space(1))) unsigned int*)(gp),           \
        (__attribute__((address_space(3))) unsigned int*)(lp), 16, 0, 0)

__device__ __forceinline__ unsigned short f2bf(float f) {
    unsigned u = __builtin_bit_cast(unsigned, f);
    u = (u + 0x7FFFu + ((u >> 16) & 1u)) >> 16;   // round-to-nearest-even
    return (unsigned short)u;
}
__device__ __forceinline__ short8 ld8(const unsigned short* p) {
    return *reinterpret_cast<const short8*>(p);
}
__device__ __forceinline__ short8 ld8b(const void* base, int byte_off) {
    return *reinterpret_cast<const short8*>((const char*)base + byte_off);
}

// ------------------------- pyramid pools of x2 -----------------------------
__global__ __launch_bounds__(64) void pool_kernel(const float* __restrict__ x2,
                                                  float* __restrict__ p1,
                                                  float* __restrict__ p2,
                                                  float* __restrict__ p4) {
    int bc = blockIdx.x;
    int t = threadIdx.x;
    const float* src = x2 + (size_t)bc * 1024;
    int dh = t >> 3, dw = t & 7;
    float s[16];
#pragma unroll
    for (int r = 0; r < 16; ++r)
        s[r] = src[((r >> 2) * 8 + dh) * 32 + (r & 3) * 8 + dw];
#pragma unroll
    for (int r = 0; r < 16; ++r) {
        float v = s[r];
        v += __shfl_xor(v, 1);  v += __shfl_xor(v, 2);  v += __shfl_xor(v, 4);
        v += __shfl_xor(v, 8);  v += __shfl_xor(v, 16); v += __shfl_xor(v, 32);
        s[r] = v;
    }
    if (t == 0) {
        float sq[4];
#pragma unroll
        for (int j = 0; j < 4; ++j) {
            int jh = j >> 1, jw = j & 1;
            sq[j] = s[8 * jh + 2 * jw] + s[8 * jh + 2 * jw + 1] +
                    s[8 * jh + 4 + 2 * jw] + s[8 * jh + 4 + 2 * jw + 1];
            p2[(size_t)bc * 4 + j] = sq[j] * (1.f / 256.f);
        }
#pragma unroll
        for (int r = 0; r < 16; ++r) p4[(size_t)bc * 16 + r] = s[r] * (1.f / 64.f);
        p1[bc] = (sq[0] + sq[1] + sq[2] + sq[3]) * (1.f / 1024.f);
    }
}

// -------- kadd[b][o][r16] = bk[o] + Wk[:,256:]·(pooled channels for r) -----
__global__ __launch_bounds__(256) void kadd_kernel(const float* __restrict__ Wk,
                                                   const float* __restrict__ bk,
                                                   const float* __restrict__ p1,
                                                   const float* __restrict__ p2,
                                                   const float* __restrict__ p4,
                                                   float* __restrict__ kadd) {
    int b = blockIdx.x >> 7, o = blockIdx.x & 127;
    int tid = threadIdx.x;
    const float* wr = Wk + (size_t)o * 1024;
    int c = tid;
    size_t bc = (size_t)b * 256 + c;
    float vals[21];
    vals[0] = wr[256 + c] * p1[bc];
    float w2 = wr[512 + c], w4 = wr[768 + c];
#pragma unroll
    for (int j = 0; j < 4; ++j) vals[1 + j] = w2 * p2[bc * 4 + j];
#pragma unroll
    for (int r = 0; r < 16; ++r) vals[5 + r] = w4 * p4[bc * 16 + r];

    int lane = tid & 63, wid = tid >> 6;
    __shared__ float red[21][4];
    __shared__ float tot[21];
#pragma unroll
    for (int k = 0; k < 21; ++k) {
        float v = vals[k];
        v += __shfl_xor(v, 1);  v += __shfl_xor(v, 2);  v += __shfl_xor(v, 4);
        v += __shfl_xor(v, 8);  v += __shfl_xor(v, 16); v += __shfl_xor(v, 32);
        if (lane == 0) red[k][wid] = v;
    }
    __syncthreads();
    if (tid < 21) tot[tid] = red[tid][0] + red[tid][1] + red[tid][2] + red[tid][3];
    __syncthreads();
    if (tid < 16) {
        int r = tid;
        int rr = ((r >> 2) >> 1) * 2 + ((r & 3) >> 1);
        kadd[((size_t)(b * 128 + o)) * 16 + r] = bk[o] + tot[0] + tot[1 + rr] + tot[5 + r];
    }
}

// ------------------ staging helpers for the fused GEMM ---------------------
// LDS layout: [row][64 c elems] rows of 128B, byte col ^= (row&7)<<4.
// stage_x: transpose+convert x [c][n] f32 -> lds [n][c] bf16 (128 n x 64 c)
__device__ __forceinline__ void stage_x(unsigned short* lds, const float* X,
                                        int n0, int kc, int tid) {
    int c4 = (tid & 15) * 4;     // c group of 4
    int ng = tid >> 4;           // n chunk of 8
    const float* src = X + (size_t)(kc + c4) * 1024 + n0 + ng * 8;
    float v[4][8];
#pragma unroll
    for (int i = 0; i < 4; ++i) {
        f32x4 a = *reinterpret_cast<const f32x4*>(src + (size_t)i * 1024);
        f32x4 bb = *reinterpret_cast<const f32x4*>(src + (size_t)i * 1024 + 4);
#pragma unroll
        for (int t = 0; t < 4; ++t) { v[i][t] = a[t]; v[i][4 + t] = bb[t]; }
    }
#pragma unroll
    for (int j = 0; j < 8; ++j) {
        int n = ng * 8 + j;
        uint2 pk;
        pk.x = (unsigned)f2bf(v[0][j]) | ((unsigned)f2bf(v[1][j]) << 16);
        pk.y = (unsigned)f2bf(v[2][j]) | ((unsigned)f2bf(v[3][j]) << 16);
        int byte = (n << 7) + (((tid & 15) * 8) ^ ((n & 7) << 4));
        *reinterpret_cast<uint2*>((char*)lds + byte) = pk;
    }
}
// stage_w: convert W [o][c] f32 -> lds [o][c] bf16 (128 o x 64 c)
__device__ __forceinline__ void stage_w(unsigned short* lds, const float* W, int ldw,
                                        int o0, int kc, int tid) {
    int o = tid >> 1, h = tid & 1;
    const float* src = W + (size_t)(o0 + o) * ldw + kc + h * 32;
    float v[32];
#pragma unroll
    for (int q = 0; q < 8; ++q) {
        f32x4 a = *reinterpret_cast<const f32x4*>(src + q * 4);
#pragma unroll
        for (int t = 0; t < 4; ++t) v[q * 4 + t] = a[t];
    }
    int swz = (o & 7) << 4;
#pragma unroll
    for (int q = 0; q < 4; ++q) {
        uint4 pk;
        pk.x = (unsigned)f2bf(v[q*8+0]) | ((unsigned)f2bf(v[q*8+1]) << 16);
        pk.y = (unsigned)f2bf(v[q*8+2]) | ((unsigned)f2bf(v[q*8+3]) << 16);
        pk.z = (unsigned)f2bf(v[q*8+4]) | ((unsigned)f2bf(v[q*8+5]) << 16);
        pk.w = (unsigned)f2bf(v[q*8+6]) | ((unsigned)f2bf(v[q*8+7]) << 16);
        int byte = (o << 7) + (((h * 64) + q * 16) ^ swz);
        *reinterpret_cast<uint4*>((char*)lds + byte) = pk;
    }
}

// ----------------- fused projection GEMM (q, k, v in one launch) -----------
// blocks 0..255: mode0 q[n,o]; 256..511: mode1 k[n,o]+kadd; 512..1023: mode2
// v[o,n]. All read f32 inputs directly (transpose+convert in staging).
__global__ __launch_bounds__(256) void gemm_kernel(const float* __restrict__ x1,
                                                   const float* __restrict__ x2,
                                                   const float* __restrict__ Wq,
                                                   const float* __restrict__ bq,
                                                   const float* __restrict__ Wk,
                                                   const float* __restrict__ Wv,
                                                   const float* __restrict__ bv,
                                                   const float* __restrict__ kadd,
                                                   unsigned short* __restrict__ qt,
                                                   unsigned short* __restrict__ kt,
                                                   unsigned short* __restrict__ vv) {
    __shared__ unsigned short alds[128 * 64];   // 16 KB
    __shared__ unsigned short blds[128 * 64];   // 16 KB

    int id = blockIdx.x;
    int mode, bx, by = 0, b;
    if (id < 256)      { mode = 0; b = id >> 3; bx = id & 7; }
    else if (id < 512) { mode = 1; b = (id - 256) >> 3; bx = (id - 256) & 7; }
    else               { int t = id - 512; mode = 2; b = t >> 4; bx = (t >> 3) & 1; by = t & 7; }

    int tid = threadIdx.x;
    int w = tid >> 6, lane = tid & 63;
    int lrow = lane & 15, lk16b = (lane >> 4) * 16;
    int swl = (lrow & 7) << 4;
    int row0 = bx * 128;
    int col0 = (mode == 2) ? by * 128 : 0;
    int wr = (w >> 1) * 64, wc = (w & 1) * 64;

    const float* X = ((mode == 0) ? x1 : x2) + (size_t)b * 262144;
    const float* Wmat = (mode == 0) ? Wq : (mode == 1) ? Wk : Wv;
    int ldw = (mode == 1) ? 1024 : 256;

    f32x4 z = {0.f, 0.f, 0.f, 0.f};
    f32x4 acc[4][4];
#pragma unroll
    for (int i = 0; i < 4; ++i)
#pragma unroll
        for (int j = 0; j < 4; ++j) acc[i][j] = z;

    for (int kc = 0; kc < 256; kc += 64) {
        if (kc) __syncthreads();
        if (mode != 2) {
            stage_x(alds, X, row0, kc, tid);        // A = x^T tile
            stage_w(blds, Wmat, ldw, 0, kc, tid);   // B = W tile
        } else {
            stage_w(alds, Wmat, ldw, row0, kc, tid); // A = Wv tile
            stage_x(blds, X, col0, kc, tid);         // B = x2^T tile
        }
        __syncthreads();

#pragma unroll
        for (int kh = 0; kh < 2; ++kh) {
            short8 af[4], bfr[4];
#pragma unroll
            for (int i = 0; i < 4; ++i)
                af[i] = ld8b(alds, ((wr + i * 16 + lrow) << 7) + (((kh << 6) + lk16b) ^ swl));
#pragma unroll
            for (int j = 0; j < 4; ++j)
                bfr[j] = ld8b(blds, ((wc + j * 16 + lrow) << 7) + (((kh << 6) + lk16b) ^ swl));
#pragma unroll
            for (int i = 0; i < 4; ++i)
#pragma unroll
                for (int j = 0; j < 4; ++j) acc[i][j] = MFMA(af[i], bfr[j], acc[i][j]);
        }
    }

    unsigned short* out = (mode == 0) ? qt + (size_t)b * 131072
                        : (mode == 1) ? kt + (size_t)b * 131072
                                      : vv + (size_t)b * 262144;
    int ldo = (mode == 2) ? 1024 : 128;
#pragma unroll
    for (int i = 0; i < 4; ++i) {
#pragma unroll
        for (int j = 0; j < 4; ++j) {
            int col = col0 + wc + j * 16 + lrow;
#pragma unroll
            for (int r = 0; r < 4; ++r) {
                int row = row0 + wr + i * 16 + (lane >> 4) * 4 + r;
                float val = acc[i][j][r];
                if (mode == 0) val += bq[col];
                if (mode == 1) {
                    int h = row >> 5, ww = row & 31;
                    val += kadd[((size_t)(b * 128 + col)) * 16 + ((h >> 3) * 4 + (ww >> 3))];
                }
                if (mode == 2) val += bv[row];
                out[(size_t)row * ldo + col] = f2bf(val);
            }
        }
    }
}

// --------------------------- flash attention -------------------------------
// XCD-affine: all 16 i-tiles of a b on one XCD (K/V L2-resident per XCD).
// K double-buffered; V fetch overlaps QK+softmax; counted vmcnt drains.
__global__ __launch_bounds__(256) void attn_kernel(const unsigned short* __restrict__ qt,
                                                   const unsigned short* __restrict__ kt,
                                                   const unsigned short* __restrict__ vv,
                                                   const float* __restrict__ x1,
                                                   float* __restrict__ out) {
    int bid = blockIdx.x;
    int lid = bid >> 3;
    int b = (bid & 7) * 4 + (lid >> 4);
    int i0 = (lid & 15) * 64;
    int tid = threadIdx.x;
    int w = tid >> 6, lane = tid & 63;
    int lrow = lane & 15, lk8 = (lane >> 4) * 8;
    int lk16b = lk8 * 2;
    int swl = (lrow & 7) << 4;
    int iw = i0 + w * 16;

    __shared__ unsigned short klds[2][64 * 128];  // 32 KB dbuf, 256B rows
    __shared__ unsigned short vlds[256 * 64];     // 32 KB, 128B rows
    __shared__ unsigned short plds[4][16][72];    // per-wave P strip

    const unsigned short* qb = qt + ((size_t)b * 1024 + iw) * 128;
    const unsigned short* kb = kt + (size_t)b * 131072;
    const unsigned short* vb = vv + (size_t)b * 262144;

    short8 qf[4];
#pragma unroll
    for (int cc = 0; cc < 4; ++cc) qf[cc] = ld8(qb + (size_t)lrow * 128 + cc * 32 + lk8);

    // staging geometry
    int soff = w * 1024 + (lane << 4);
    int krow0 = soff >> 8;
    int kcol = ((soff & 255) ^ ((krow0 & 7) << 4)) >> 1;
    int vrow0 = soff >> 7;
    int vcol = ((soff & 127) ^ ((vrow0 & 7) << 4)) >> 1;

    f32x4 z = {0.f, 0.f, 0.f, 0.f};
    f32x4 oacc[16];
#pragma unroll
    for (int cb = 0; cb < 16; ++cb) oacc[cb] = z;
    float m_[4] = {-1e30f, -1e30f, -1e30f, -1e30f};
    float l_[4] = {0.f, 0.f, 0.f, 0.f};

    // prologue: stage K(0) into buf 0
#pragma unroll
    for (int it = 0; it < 4; ++it)
        GLOAD16(kb + (size_t)(it * 16 + krow0) * 128 + kcol,
                (char*)klds + it * 4096 + w * 1024);

    int cur = 0;
    for (int j0 = 0; j0 < 1024; j0 += 64) {
        // A/B: K(j) landed everywhere (each wave drains own, barrier syncs)
        asm volatile("s_waitcnt vmcnt(0)" ::: "memory");
        __syncthreads();

        // C: issue V(j) — overlaps QK + softmax
#pragma unroll
        for (int it = 0; it < 8; ++it)
            GLOAD16(vb + (size_t)(it * 32 + vrow0) * 1024 + j0 + vcol,
                    (char*)vlds + it * 4096 + w * 1024);

        // D: QK from klds[cur]
        const char* kbase = (const char*)klds + cur * 16384;
        f32x4 s[4];
#pragma unroll
        for (int jb = 0; jb < 4; ++jb) s[jb] = z;
#pragma unroll
        for (int jb = 0; jb < 4; ++jb) {
            int jrow = jb * 16 + lrow;
#pragma unroll
            for (int cc = 0; cc < 4; ++cc) {
                short8 kf = ld8b(kbase, (jrow << 8) + (((cc << 6) + lk16b) ^ swl));
                s[jb] = MFMA(qf[cc], kf, s[jb]);
            }
        }

        // E: issue K(j+1) into other buffer (wraps harmlessly at the end)
        int jn = (j0 + 64) & 1023;
#pragma unroll
        for (int it = 0; it < 4; ++it)
            GLOAD16(kb + (size_t)(jn + it * 16 + krow0) * 128 + kcol,
                    (char*)klds + (cur ^ 1) * 16384 + it * 4096 + w * 1024);

        // F: online softmax with defer-max (skip rescale if max grew <= 8)
        float tmax[4];
#pragma unroll
        for (int r = 0; r < 4; ++r) {
            float t = fmaxf(fmaxf(s[0][r], s[1][r]), fmaxf(s[2][r], s[3][r]));
            t = fmaxf(t, __shfl_xor(t, 1));
            t = fmaxf(t, __shfl_xor(t, 2));
            t = fmaxf(t, __shfl_xor(t, 4));
            t = fmaxf(t, __shfl_xor(t, 8));
            tmax[r] = t;
        }
        bool ok = (tmax[0] <= m_[0] + 8.f) && (tmax[1] <= m_[1] + 8.f) &&
                  (tmax[2] <= m_[2] + 8.f) && (tmax[3] <= m_[3] + 8.f);
        if (!__all(ok)) {
#pragma unroll
            for (int r = 0; r < 4; ++r) {
                float nm = fmaxf(m_[r], tmax[r]);
                float sc = __expf(m_[r] - nm);
                m_[r] = nm;
                l_[r] *= sc;
#pragma unroll
                for (int cb = 0; cb < 16; ++cb) oacc[cb][r] *= sc;
            }
        }
        float rs[4] = {0.f, 0.f, 0.f, 0.f};
#pragma unroll
        for (int jb = 0; jb < 4; ++jb)
#pragma unroll
            for (int r = 0; r < 4; ++r) {
                float p = __expf(s[jb][r] - m_[r]);
                rs[r] += p;
                plds[w][(lane >> 4) * 4 + r][jb * 16 + lrow] = f2bf(p);
            }
#pragma unroll
        for (int r = 0; r < 4; ++r) {
            float t = rs[r];
            t += __shfl_xor(t, 1);
            t += __shfl_xor(t, 2);
            t += __shfl_xor(t, 4);
            t += __shfl_xor(t, 8);
            l_[r] += t;
        }

        // G/H: drain V (leave K(j+1)'s 4 loads in flight), sync
        asm volatile("s_waitcnt vmcnt(4)" ::: "memory");
        __syncthreads();

        // I: PV from vlds
        short8 pa0 = ld8(&plds[w][lrow][lk8]);
        short8 pa1 = ld8(&plds[w][lrow][32 + lk8]);
#pragma unroll
        for (int cb = 0; cb < 16; ++cb) {
            int c = cb * 16 + lrow;
            short8 vf0 = ld8b(vlds, (c << 7) + (lk16b ^ swl));
            oacc[cb] = MFMA(pa0, vf0, oacc[cb]);
            short8 vf1 = ld8b(vlds, (c << 7) + ((64 + lk16b) ^ swl));
            oacc[cb] = MFMA(pa1, vf1, oacc[cb]);
        }
        cur ^= 1;
    }
    asm volatile("s_waitcnt vmcnt(0)" ::: "memory");   // drain wrapped K loads

    // epilogue: direct float4 stores (4 consecutive i per lane) + residual
    float inv[4];
#pragma unroll
    for (int r = 0; r < 4; ++r) inv[r] = 1.f / l_[r];
    int ib = iw + (lane >> 4) * 4;
#pragma unroll
    for (int cb = 0; cb < 16; ++cb) {
        int c = cb * 16 + lrow;
        size_t g = ((size_t)b * 256 + c) * 1024 + ib;
        f32x4 xv = *reinterpret_cast<const f32x4*>(x1 + g);
        f32x4 res;
#pragma unroll
        for (int r = 0; r < 4; ++r) res[r] = oacc[cb][r] * inv[r] + xv[r];
        *reinterpret_cast<f32x4*>(out + g) = res;
    }
}

// ---------------------------------------------------------------------------
extern "C" void kernel_launch(void* const* d_in, const int* in_sizes, int n_in,
                              void* d_out, int out_size, void* d_ws, size_t ws_size,
                              hipStream_t stream) {
    const float* x1 = (const float*)d_in[0];
    const float* x2 = (const float*)d_in[1];
    const float* Wq = (const float*)d_in[2];
    const float* bq = (const float*)d_in[3];
    const float* Wk = (const float*)d_in[4];
    const float* bk = (const float*)d_in[5];
    const float* Wv = (const float*)d_in[6];
    const float* bv = (const float*)d_in[7];
    float* out = (float*)d_out;

    char* ws = (char*)d_ws;
    unsigned short* qt = (unsigned short*)(ws + 0);         // 8 MiB
    unsigned short* kt = (unsigned short*)(ws + 8388608);   // 8 MiB
    unsigned short* v  = (unsigned short*)(ws + 16777216);  // 16 MiB
    float* p1   = (float*)(ws + 33554432);                  // 32 KiB
    float* p2   = (float*)(ws + 33587200);                  // 128 KiB
    float* p4   = (float*)(ws + 33718272);                  // 512 KiB
    float* kadd = (float*)(ws + 34242560);                  // 256 KiB

    pool_kernel<<<8192, 64, 0, stream>>>(x2, p1, p2, p4);
    kadd_kernel<<<4096, 256, 0, stream>>>(Wk, bk, p1, p2, p4, kadd);
    gemm_kernel<<<1024, 256, 0, stream>>>(x1, x2, Wq, bq, Wk, Wv, bv, kadd, qt, kt, v);
    attn_kernel<<<512, 256, 0, stream>>>(qt, kt, v, x1, out);
}

// Round 6
// 259.128 us; speedup vs baseline: 1.5842x; 1.0085x over previous
//
#include <hip/hip_runtime.h>

// ---------------------------------------------------------------------------
// CrossAttention: B=32, C=256, H=W=32 (HW=1024), Cq=128
// out[b,c,i] = sum_j v[b,c,j] * softmax_j(q^T k)[i,j] + x1[b,c,i]
// R5b: (R5 + compile fix: ldw helper renamed ldw_tile, no shadowing)
//   gemm: reg-prefetch pipeline (T14) + v_cvt_pk_bf16_f32 packing;
//   pool: 256-thread blocks. Attn unchanged (expose its counters).
// ---------------------------------------------------------------------------

typedef __attribute__((ext_vector_type(8))) short short8;    // 8 bf16
typedef __attribute__((ext_vector_type(4))) float f32x4;

#define MFMA(a, b, c) __builtin_amdgcn_mfma_f32_16x16x32_bf16((a), (b), (c), 0, 0, 0)

#define GLOAD16(gp, lp)                                                        \
    __builtin_amdgcn_global_load_lds(                                          \
        (const __attribute__((address_space(1))) unsigned int*)(gp),           \
        (__attribute__((address_space(3))) unsigned int*)(lp), 16, 0, 0)

__device__ __forceinline__ unsigned short f2bf(float f) {
    unsigned u = __builtin_bit_cast(unsigned, f);
    u = (u + 0x7FFFu + ((u >> 16) & 1u)) >> 16;   // round-to-nearest-even
    return (unsigned short)u;
}
// packed f32x2 -> bf16x2 (RTNE), single HW instr on gfx950
__device__ __forceinline__ unsigned cvt_pk(float lo, float hi) {
    unsigned r;
    asm("v_cvt_pk_bf16_f32 %0, %1, %2" : "=v"(r) : "v"(lo), "v"(hi));
    return r;
}
__device__ __forceinline__ short8 ld8(const unsigned short* p) {
    return *reinterpret_cast<const short8*>(p);
}
__device__ __forceinline__ short8 ld8b(const void* base, int byte_off) {
    return *reinterpret_cast<const short8*>((const char*)base + byte_off);
}

// ------------------------- pyramid pools of x2 -----------------------------
// 256-thread blocks; wave w handles (b,c) pair blockIdx*4+w.
__global__ __launch_bounds__(256) void pool_kernel(const float* __restrict__ x2,
                                                   float* __restrict__ p1,
                                                   float* __restrict__ p2,
                                                   float* __restrict__ p4) {
    int w = threadIdx.x >> 6, t = threadIdx.x & 63;
    int bc = blockIdx.x * 4 + w;
    const float* src = x2 + (size_t)bc * 1024;
    int dh = t >> 3, dw = t & 7;
    float s[16];
#pragma unroll
    for (int r = 0; r < 16; ++r)
        s[r] = src[((r >> 2) * 8 + dh) * 32 + (r & 3) * 8 + dw];
#pragma unroll
    for (int r = 0; r < 16; ++r) {
        float v = s[r];
        v += __shfl_xor(v, 1);  v += __shfl_xor(v, 2);  v += __shfl_xor(v, 4);
        v += __shfl_xor(v, 8);  v += __shfl_xor(v, 16); v += __shfl_xor(v, 32);
        s[r] = v;
    }
    if (t == 0) {
        float sq[4];
#pragma unroll
        for (int j = 0; j < 4; ++j) {
            int jh = j >> 1, jw = j & 1;
            sq[j] = s[8 * jh + 2 * jw] + s[8 * jh + 2 * jw + 1] +
                    s[8 * jh + 4 + 2 * jw] + s[8 * jh + 4 + 2 * jw + 1];
            p2[(size_t)bc * 4 + j] = sq[j] * (1.f / 256.f);
        }
#pragma unroll
        for (int r = 0; r < 16; ++r) p4[(size_t)bc * 16 + r] = s[r] * (1.f / 64.f);
        p1[bc] = (sq[0] + sq[1] + sq[2] + sq[3]) * (1.f / 1024.f);
    }
}

// -------- kadd[b][o][r16] = bk[o] + Wk[:,256:]·(pooled channels for r) -----
__global__ __launch_bounds__(256) void kadd_kernel(const float* __restrict__ Wk,
                                                   const float* __restrict__ bk,
                                                   const float* __restrict__ p1,
                                                   const float* __restrict__ p2,
                                                   const float* __restrict__ p4,
                                                   float* __restrict__ kadd) {
    int b = blockIdx.x >> 7, o = blockIdx.x & 127;
    int tid = threadIdx.x;
    const float* wr = Wk + (size_t)o * 1024;
    int c = tid;
    size_t bc = (size_t)b * 256 + c;
    float vals[21];
    vals[0] = wr[256 + c] * p1[bc];
    float w2 = wr[512 + c], w4 = wr[768 + c];
#pragma unroll
    for (int j = 0; j < 4; ++j) vals[1 + j] = w2 * p2[bc * 4 + j];
#pragma unroll
    for (int r = 0; r < 16; ++r) vals[5 + r] = w4 * p4[bc * 16 + r];

    int lane = tid & 63, wid = tid >> 6;
    __shared__ float red[21][4];
    __shared__ float tot[21];
#pragma unroll
    for (int k = 0; k < 21; ++k) {
        float v = vals[k];
        v += __shfl_xor(v, 1);  v += __shfl_xor(v, 2);  v += __shfl_xor(v, 4);
        v += __shfl_xor(v, 8);  v += __shfl_xor(v, 16); v += __shfl_xor(v, 32);
        if (lane == 0) red[k][wid] = v;
    }
    __syncthreads();
    if (tid < 21) tot[tid] = red[tid][0] + red[tid][1] + red[tid][2] + red[tid][3];
    __syncthreads();
    if (tid < 16) {
        int r = tid;
        int rr = ((r >> 2) >> 1) * 2 + ((r & 3) >> 1);
        kadd[((size_t)(b * 128 + o)) * 16 + r] = bk[o] + tot[0] + tot[1 + rr] + tot[5 + r];
    }
}

// ------------------ staging helpers for the fused GEMM ---------------------
// x: [c][n] f32 -> regs (4 c-rows x 8 n per thread)
__device__ __forceinline__ void ldx(const float* X, int n0, int kc, int tid,
                                    float v[32]) {
    int c4 = (tid & 15) * 4, ng = tid >> 4;
    const float* src = X + (size_t)(kc + c4) * 1024 + n0 + ng * 8;
#pragma unroll
    for (int i = 0; i < 4; ++i) {
        f32x4 a = *reinterpret_cast<const f32x4*>(src + (size_t)i * 1024);
        f32x4 b = *reinterpret_cast<const f32x4*>(src + (size_t)i * 1024 + 4);
#pragma unroll
        for (int t = 0; t < 4; ++t) { v[i * 8 + t] = a[t]; v[i * 8 + 4 + t] = b[t]; }
    }
}
// regs -> lds [n][c] bf16, swizzled (byte ^= (n&7)<<4)
__device__ __forceinline__ void packx(unsigned short* lds, int tid, const float v[32]) {
    int c8b = (tid & 15) * 8, ng = tid >> 4;
#pragma unroll
    for (int j = 0; j < 8; ++j) {
        int n = ng * 8 + j;
        uint2 pk;
        pk.x = cvt_pk(v[0 * 8 + j], v[1 * 8 + j]);
        pk.y = cvt_pk(v[2 * 8 + j], v[3 * 8 + j]);
        *reinterpret_cast<uint2*>((char*)lds + (n << 7) + (c8b ^ ((n & 7) << 4))) = pk;
    }
}
// W: [o][c] f32 -> regs (1 o-row x 32 c per thread)
__device__ __forceinline__ void ldw_tile(const float* W, int ldW, int o0, int kc,
                                         int tid, float v[32]) {
    int o = tid >> 1, h = tid & 1;
    const float* src = W + (size_t)(o0 + o) * ldW + kc + h * 32;
#pragma unroll
    for (int q = 0; q < 8; ++q) {
        f32x4 a = *reinterpret_cast<const f32x4*>(src + q * 4);
#pragma unroll
        for (int t = 0; t < 4; ++t) v[q * 4 + t] = a[t];
    }
}
// regs -> lds [o][c] bf16, swizzled
__device__ __forceinline__ void packw(unsigned short* lds, int tid, const float v[32]) {
    int o = tid >> 1, h = tid & 1, swz = (o & 7) << 4;
#pragma unroll
    for (int q = 0; q < 4; ++q) {
        uint4 pk;
        pk.x = cvt_pk(v[q * 8 + 0], v[q * 8 + 1]);
        pk.y = cvt_pk(v[q * 8 + 2], v[q * 8 + 3]);
        pk.z = cvt_pk(v[q * 8 + 4], v[q * 8 + 5]);
        pk.w = cvt_pk(v[q * 8 + 6], v[q * 8 + 7]);
        *reinterpret_cast<uint4*>((char*)lds + (o << 7) + (((h * 64) + q * 16) ^ swz)) = pk;
    }
}

// ----------------- fused projection GEMM (q, k, v in one launch) -----------
// blocks 0..255: mode0 q[n,o]; 256..511: mode1 k[n,o]+kadd; 512..1023: mode2
// v[o,n]. f32 in; transpose+convert in staging. x-tile loads prefetched one
// k-step ahead (T14); W loads JIT (L2-hot).
__global__ __launch_bounds__(256) void gemm_kernel(const float* __restrict__ x1,
                                                   const float* __restrict__ x2,
                                                   const float* __restrict__ Wq,
                                                   const float* __restrict__ bq,
                                                   const float* __restrict__ Wk,
                                                   const float* __restrict__ Wv,
                                                   const float* __restrict__ bv,
                                                   const float* __restrict__ kadd,
                                                   unsigned short* __restrict__ qt,
                                                   unsigned short* __restrict__ kt,
                                                   unsigned short* __restrict__ vv) {
    __shared__ unsigned short alds[128 * 64];   // 16 KB
    __shared__ unsigned short blds[128 * 64];   // 16 KB

    int id = blockIdx.x;
    int mode, bx, by = 0, b;
    if (id < 256)      { mode = 0; b = id >> 3; bx = id & 7; }
    else if (id < 512) { mode = 1; b = (id - 256) >> 3; bx = (id - 256) & 7; }
    else               { int t = id - 512; mode = 2; b = t >> 4; bx = (t >> 3) & 1; by = t & 7; }

    int tid = threadIdx.x;
    int w = tid >> 6, lane = tid & 63;
    int lrow = lane & 15, lk16b = (lane >> 4) * 16;
    int swl = (lrow & 7) << 4;
    int row0 = bx * 128;
    int col0 = (mode == 2) ? by * 128 : 0;
    int wr = (w >> 1) * 64, wc = (w & 1) * 64;

    const float* X = ((mode == 0) ? x1 : x2) + (size_t)b * 262144;
    const float* Wmat = (mode == 0) ? Wq : (mode == 1) ? Wk : Wv;
    int ldW = (mode == 1) ? 1024 : 256;
    int xbase = (mode == 2) ? col0 : row0;      // x-tile origin in n
    int wbase = (mode == 2) ? row0 : 0;         // W-tile origin in o
    unsigned short* xl = (mode == 2) ? blds : alds;
    unsigned short* wl = (mode == 2) ? alds : blds;

    f32x4 z = {0.f, 0.f, 0.f, 0.f};
    f32x4 acc[4][4];
#pragma unroll
    for (int i = 0; i < 4; ++i)
#pragma unroll
        for (int j = 0; j < 4; ++j) acc[i][j] = z;

    float xv[32], wv[32];
    ldx(X, xbase, 0, tid, xv);                  // prologue prefetch

    for (int kc = 0; kc < 256; kc += 64) {
        ldw_tile(Wmat, ldW, wbase, kc, tid, wv); // JIT, L2-hot (~200cy, hidden)
        if (kc) __syncthreads();                 // prev tile readers done
        packx(xl, tid, xv);
        packw(wl, tid, wv);
        if (kc < 192) ldx(X, xbase, kc + 64, tid, xv);  // prefetch next
        __syncthreads();

#pragma unroll
        for (int kh = 0; kh < 2; ++kh) {
            short8 af[4], bfr[4];
#pragma unroll
            for (int i = 0; i < 4; ++i)
                af[i] = ld8b(alds, ((wr + i * 16 + lrow) << 7) + (((kh << 6) + lk16b) ^ swl));
#pragma unroll
            for (int j = 0; j < 4; ++j)
                bfr[j] = ld8b(blds, ((wc + j * 16 + lrow) << 7) + (((kh << 6) + lk16b) ^ swl));
#pragma unroll
            for (int i = 0; i < 4; ++i)
#pragma unroll
                for (int j = 0; j < 4; ++j) acc[i][j] = MFMA(af[i], bfr[j], acc[i][j]);
        }
    }

    unsigned short* out = (mode == 0) ? qt + (size_t)b * 131072
                        : (mode == 1) ? kt + (size_t)b * 131072
                                      : vv + (size_t)b * 262144;
    int ldo = (mode == 2) ? 1024 : 128;
#pragma unroll
    for (int i = 0; i < 4; ++i) {
#pragma unroll
        for (int j = 0; j < 4; ++j) {
            int col = col0 + wc + j * 16 + lrow;
#pragma unroll
            for (int r = 0; r < 4; ++r) {
                int row = row0 + wr + i * 16 + (lane >> 4) * 4 + r;
                float val = acc[i][j][r];
                if (mode == 0) val += bq[col];
                if (mode == 1) {
                    int h = row >> 5, ww = row & 31;
                    val += kadd[((size_t)(b * 128 + col)) * 16 + ((h >> 3) * 4 + (ww >> 3))];
                }
                if (mode == 2) val += bv[row];
                out[(size_t)row * ldo + col] = f2bf(val);
            }
        }
    }
}

// --------------------------- flash attention -------------------------------
// XCD-affine: all 16 i-tiles of a b on one XCD (K/V ~3MB per 4 b's: L2-fit).
// K double-buffered; V fetch overlaps QK+softmax; counted vmcnt drains.
__global__ __launch_bounds__(256) void attn_kernel(const unsigned short* __restrict__ qt,
                                                   const unsigned short* __restrict__ kt,
                                                   const unsigned short* __restrict__ vv,
                                                   const float* __restrict__ x1,
                                                   float* __restrict__ out) {
    int bid = blockIdx.x;
    int lid = bid >> 3;
    int b = (bid & 7) * 4 + (lid >> 4);
    int i0 = (lid & 15) * 64;
    int tid = threadIdx.x;
    int w = tid >> 6, lane = tid & 63;
    int lrow = lane & 15, lk8 = (lane >> 4) * 8;
    int lk16b = lk8 * 2;
    int swl = (lrow & 7) << 4;
    int iw = i0 + w * 16;

    __shared__ unsigned short klds[2][64 * 128];  // 32 KB dbuf, 256B rows
    __shared__ unsigned short vlds[256 * 64];     // 32 KB, 128B rows
    __shared__ unsigned short plds[4][16][72];    // per-wave P strip

    const unsigned short* qb = qt + ((size_t)b * 1024 + iw) * 128;
    const unsigned short* kb = kt + (size_t)b * 131072;
    const unsigned short* vb = vv + (size_t)b * 262144;

    short8 qf[4];
#pragma unroll
    for (int cc = 0; cc < 4; ++cc) qf[cc] = ld8(qb + (size_t)lrow * 128 + cc * 32 + lk8);

    int soff = w * 1024 + (lane << 4);
    int krow0 = soff >> 8;
    int kcol = ((soff & 255) ^ ((krow0 & 7) << 4)) >> 1;
    int vrow0 = soff >> 7;
    int vcol = ((soff & 127) ^ ((vrow0 & 7) << 4)) >> 1;

    f32x4 z = {0.f, 0.f, 0.f, 0.f};
    f32x4 oacc[16];
#pragma unroll
    for (int cb = 0; cb < 16; ++cb) oacc[cb] = z;
    float m_[4] = {-1e30f, -1e30f, -1e30f, -1e30f};
    float l_[4] = {0.f, 0.f, 0.f, 0.f};

#pragma unroll
    for (int it = 0; it < 4; ++it)
        GLOAD16(kb + (size_t)(it * 16 + krow0) * 128 + kcol,
                (char*)klds + it * 4096 + w * 1024);

    int cur = 0;
    for (int j0 = 0; j0 < 1024; j0 += 64) {
        asm volatile("s_waitcnt vmcnt(0)" ::: "memory");
        __syncthreads();

#pragma unroll
        for (int it = 0; it < 8; ++it)
            GLOAD16(vb + (size_t)(it * 32 + vrow0) * 1024 + j0 + vcol,
                    (char*)vlds + it * 4096 + w * 1024);

        const char* kbase = (const char*)klds + cur * 16384;
        f32x4 s[4];
#pragma unroll
        for (int jb = 0; jb < 4; ++jb) s[jb] = z;
#pragma unroll
        for (int jb = 0; jb < 4; ++jb) {
            int jrow = jb * 16 + lrow;
#pragma unroll
            for (int cc = 0; cc < 4; ++cc) {
                short8 kf = ld8b(kbase, (jrow << 8) + (((cc << 6) + lk16b) ^ swl));
                s[jb] = MFMA(qf[cc], kf, s[jb]);
            }
        }

        int jn = (j0 + 64) & 1023;
#pragma unroll
        for (int it = 0; it < 4; ++it)
            GLOAD16(kb + (size_t)(jn + it * 16 + krow0) * 128 + kcol,
                    (char*)klds + (cur ^ 1) * 16384 + it * 4096 + w * 1024);

        float tmax[4];
#pragma unroll
        for (int r = 0; r < 4; ++r) {
            float t = fmaxf(fmaxf(s[0][r], s[1][r]), fmaxf(s[2][r], s[3][r]));
            t = fmaxf(t, __shfl_xor(t, 1));
            t = fmaxf(t, __shfl_xor(t, 2));
            t = fmaxf(t, __shfl_xor(t, 4));
            t = fmaxf(t, __shfl_xor(t, 8));
            tmax[r] = t;
        }
        bool ok = (tmax[0] <= m_[0] + 8.f) && (tmax[1] <= m_[1] + 8.f) &&
                  (tmax[2] <= m_[2] + 8.f) && (tmax[3] <= m_[3] + 8.f);
        if (!__all(ok)) {
#pragma unroll
            for (int r = 0; r < 4; ++r) {
                float nm = fmaxf(m_[r], tmax[r]);
                float sc = __expf(m_[r] - nm);
                m_[r] = nm;
                l_[r] *= sc;
#pragma unroll
                for (int cb = 0; cb < 16; ++cb) oacc[cb][r] *= sc;
            }
        }
        float rs[4] = {0.f, 0.f, 0.f, 0.f};
#pragma unroll
        for (int jb = 0; jb < 4; ++jb)
#pragma unroll
            for (int r = 0; r < 4; ++r) {
                float p = __expf(s[jb][r] - m_[r]);
                rs[r] += p;
                plds[w][(lane >> 4) * 4 + r][jb * 16 + lrow] = f2bf(p);
            }
#pragma unroll
        for (int r = 0; r < 4; ++r) {
            float t = rs[r];
            t += __shfl_xor(t, 1);
            t += __shfl_xor(t, 2);
            t += __shfl_xor(t, 4);
            t += __shfl_xor(t, 8);
            l_[r] += t;
        }

        asm volatile("s_waitcnt vmcnt(4)" ::: "memory");
        __syncthreads();

        short8 pa0 = ld8(&plds[w][lrow][lk8]);
        short8 pa1 = ld8(&plds[w][lrow][32 + lk8]);
#pragma unroll
        for (int cb = 0; cb < 16; ++cb) {
            int c = cb * 16 + lrow;
            short8 vf0 = ld8b(vlds, (c << 7) + (lk16b ^ swl));
            oacc[cb] = MFMA(pa0, vf0, oacc[cb]);
            short8 vf1 = ld8b(vlds, (c << 7) + ((64 + lk16b) ^ swl));
            oacc[cb] = MFMA(pa1, vf1, oacc[cb]);
        }
        cur ^= 1;
    }
    asm volatile("s_waitcnt vmcnt(0)" ::: "memory");

    float inv[4];
#pragma unroll
    for (int r = 0; r < 4; ++r) inv[r] = 1.f / l_[r];
    int ib = iw + (lane >> 4) * 4;
#pragma unroll
    for (int cb = 0; cb < 16; ++cb) {
        int c = cb * 16 + lrow;
        size_t g = ((size_t)b * 256 + c) * 1024 + ib;
        f32x4 xv = *reinterpret_cast<const f32x4*>(x1 + g);
        f32x4 res;
#pragma unroll
        for (int r = 0; r < 4; ++r) res[r] = oacc[cb][r] * inv[r] + xv[r];
        *reinterpret_cast<f32x4*>(out + g) = res;
    }
}

// ---------------------------------------------------------------------------
extern "C" void kernel_launch(void* const* d_in, const int* in_sizes, int n_in,
                              void* d_out, int out_size, void* d_ws, size_t ws_size,
                              hipStream_t stream) {
    const float* x1 = (const float*)d_in[0];
    const float* x2 = (const float*)d_in[1];
    const float* Wq = (const float*)d_in[2];
    const float* bq = (const float*)d_in[3];
    const float* Wk = (const float*)d_in[4];
    const float* bk = (const float*)d_in[5];
    const float* Wv = (const float*)d_in[6];
    const float* bv = (const float*)d_in[7];
    float* out = (float*)d_out;

    char* ws = (char*)d_ws;
    unsigned short* qt = (unsigned short*)(ws + 0);         // 8 MiB
    unsigned short* kt = (unsigned short*)(ws + 8388608);   // 8 MiB
    unsigned short* v  = (unsigned short*)(ws + 16777216);  // 16 MiB
    float* p1   = (float*)(ws + 33554432);                  // 32 KiB
    float* p2   = (float*)(ws + 33587200);                  // 128 KiB
    float* p4   = (float*)(ws + 33718272);                  // 512 KiB
    float* kadd = (float*)(ws + 34242560);                  // 256 KiB

    pool_kernel<<<2048, 256, 0, stream>>>(x2, p1, p2, p4);
    kadd_kernel<<<4096, 256, 0, stream>>>(Wk, bk, p1, p2, p4, kadd);
    gemm_kernel<<<1024, 256, 0, stream>>>(x1, x2, Wq, bq, Wk, Wv, bv, kadd, qt, kt, v);
    attn_kernel<<<512, 256, 0, stream>>>(qt, kt, v, x1, out);
}